// Round 13
// baseline (63.067 us; speedup 1.0000x reference)
//
#include <hip/hip_runtime.h>

#define THREADS 512   // 2 independent 256-thread row-teams per block
#define PI_F 3.14159265358979323846f
#define RT2O2 0.70710678118654752440f

// Complex as native 2-float vector -> packed fp32 (v_pk_add/fma_f32).
typedef float cpx __attribute__((ext_vector_type(2)));

__device__ __forceinline__ cpx cmul(cpx a, cpx b) {
    cpx r = cpx{a.x, a.x} * b;
    return r + cpx{-a.y, a.y} * cpx{b.y, b.x};
}
__device__ __forceinline__ cpx mulni(cpx a) { return cpx{a.y, -a.x}; }   // * (-i)
__device__ __forceinline__ cpx mulpi(cpx a) { return cpx{-a.y, a.x}; }   // * (+i)

// XOR swizzle on cpx index (8B units): bits [3:1] ^= (bits[6:4]^bits[10:8]).
// Bit 0 untouched -> cpx-pair (float4) contiguity preserved. (R10 version —
// matched to the radix-16 stride patterns; measured 1.0e6 conflicts.)
__device__ __forceinline__ int SW(int i) { return i ^ ((((i >> 4) ^ (i >> 8)) & 7) << 1); }

__device__ __forceinline__ cpx ldb(const cpx* b, int i) { return b[SW(i)]; }
__device__ __forceinline__ void stb(cpx* b, int i, cpx v) { b[SW(i)] = v; }

// cos/sin(pi*s/16) and cos/sin(pi*s/64), s = 0..15 (compile-time folded).
constexpr float C16[16] = {
    1.f, 0.98078528040323044f, 0.92387953251128674f, 0.83146961230254524f,
    RT2O2, 0.55557023301960222f, 0.38268343236508978f, 0.19509032201612827f,
    0.f, -0.19509032201612827f, -0.38268343236508978f, -0.55557023301960222f,
    -RT2O2, -0.83146961230254524f, -0.92387953251128674f, -0.98078528040323044f};
constexpr float S16[16] = {
    0.f, 0.19509032201612827f, 0.38268343236508978f, 0.55557023301960222f,
    RT2O2, 0.83146961230254524f, 0.92387953251128674f, 0.98078528040323044f,
    1.f, 0.98078528040323044f, 0.92387953251128674f, 0.83146961230254524f,
    RT2O2, 0.55557023301960222f, 0.38268343236508978f, 0.19509032201612827f};
constexpr float C64[16] = {
    1.f, 0.99879545620517239f, 0.99518472667219693f, 0.98917650996478101f,
    0.98078528040323044f, 0.97003125319454397f, 0.95694033573220886f, 0.94154406518302081f,
    0.92387953251128674f, 0.90398929312344334f, 0.88192126434835503f, 0.85772861000027212f,
    0.83146961230254524f, 0.80320753148064494f, 0.77301045336273699f, 0.74095112535495911f};
constexpr float S64[16] = {
    0.f, 0.04906767432741801f, 0.09801714032956060f, 0.14673047445536175f,
    0.19509032201612827f, 0.24298017990326390f, 0.29028467725446233f, 0.33688985339222005f,
    0.38268343236508978f, 0.42755509343028208f, 0.47139673682599764f, 0.51410274419322166f,
    0.55557023301960222f, 0.59569930449243336f, 0.63439328416364549f, 0.67155895484701833f};

// In-place 16-point DFT, natural order in/out: z[s] = sum_n z[n] W16^{ns}
__device__ __forceinline__ void dft16(cpx* z) {
    cpx t[4][4];
#pragma unroll
    for (int n0 = 0; n0 < 4; ++n0) {
        cpx a = z[n0], b = z[4 + n0], c = z[8 + n0], d = z[12 + n0];
        cpx apc = a + c, amc = a - c, bpd = b + d, bmd = b - d;
        t[n0][0] = apc + bpd;
        t[n0][1] = amc + mulni(bmd);
        t[n0][2] = apc - bpd;
        t[n0][3] = amc + mulpi(bmd);
    }
    const cpx W1 = {0.92387953251128674f, -0.38268343236508978f};
    const cpx W2 = {RT2O2, -RT2O2};
    const cpx W3 = {0.38268343236508978f, -0.92387953251128674f};
    const cpx W6 = {-RT2O2, -RT2O2};
    const cpx W9 = {-0.92387953251128674f, 0.38268343236508978f};
    t[1][1] = cmul(t[1][1], W1); t[1][2] = cmul(t[1][2], W2); t[1][3] = cmul(t[1][3], W3);
    t[2][1] = cmul(t[2][1], W2); t[2][2] = mulni(t[2][2]);    t[2][3] = cmul(t[2][3], W6);
    t[3][1] = cmul(t[3][1], W3); t[3][2] = cmul(t[3][2], W6); t[3][3] = cmul(t[3][3], W9);
#pragma unroll
    for (int s0 = 0; s0 < 4; ++s0) {
        cpx a = t[0][s0], b = t[1][s0], c = t[2][s0], d = t[3][s0];
        cpx apc = a + c, amc = a - c, bpd = b + d, bmd = b - d;
        z[s0]      = apc + bpd;
        z[s0 + 4]  = amc + mulni(bmd);
        z[s0 + 8]  = apc - bpd;
        z[s0 + 12] = amc + mulpi(bmd);
    }
}

// z[s] *= w1^s, s=1..15; powers via squaring tree (dep depth ~4, not 15).
__device__ __forceinline__ void twiddle16(cpx* z, float theta) {
    float s_, c_;
    __sincosf(theta, &s_, &c_);
    cpx w1 = {c_, s_};
    cpx w2 = cmul(w1, w1), w3 = cmul(w1, w2), w4 = cmul(w2, w2);
    cpx w5 = cmul(w1, w4), w6 = cmul(w2, w4), w7 = cmul(w3, w4), w8 = cmul(w4, w4);
    cpx w9 = cmul(w1, w8), w10 = cmul(w2, w8), w11 = cmul(w3, w8), w12 = cmul(w4, w8);
    cpx w13 = cmul(w5, w8), w14 = cmul(w6, w8), w15 = cmul(w7, w8);
    z[1] = cmul(z[1], w1);   z[2] = cmul(z[2], w2);   z[3] = cmul(z[3], w3);
    z[4] = cmul(z[4], w4);   z[5] = cmul(z[5], w5);   z[6] = cmul(z[6], w6);
    z[7] = cmul(z[7], w7);   z[8] = cmul(z[8], w8);   z[9] = cmul(z[9], w9);
    z[10] = cmul(z[10], w10); z[11] = cmul(z[11], w11); z[12] = cmul(z[12], w12);
    z[13] = cmul(z[13], w13); z[14] = cmul(z[14], w14); z[15] = cmul(z[15], w15);
}

// Two rows per block (R10 per-row structure; occupancy-packing experiment).
// Each 256-thread team runs one row's DST-II via N/2=4096 complex FFT
// (radices 16,16,16) in its own 32 KiB LDS half:
//   v = Makhoul(sign*x); z[m] = v[2m] + i*v[2m+1]; Z = FFT_4096(z)
//   V[k] = Ze[k] + e^{-i pi k/4096} Zo[k]; out[8191-k] = Re(V[k] e^{-i pi k/16384})
// Thread t holds Z[t+256s] after stage 3 (block nibswap(t), in-place RMW);
// Hermitian partner set Z[4096-k] lives in team-thread (256-t)'s block.
// __syncthreads spans both teams; identical phase structure -> no divergence.
__global__ __launch_bounds__(THREADS) void dst_fft_kernel(const float* __restrict__ x,
                                                          float* __restrict__ out) {
    __shared__ __align__(16) cpx buf2[2][4096];  // 64 KiB

    const int team = threadIdx.x >> 8;
    const int t = threadIdx.x & 255;
    const int row = 2 * blockIdx.x + team;
    cpx* buf = buf2[team];
    const float* __restrict__ xr = x + (size_t)row * 8192;
    float* __restrict__ yr = out + (size_t)row * 8192;

    cpx z[16];

    // ---- load in stage-1 butterfly order: m = t + 256u ----
#pragma unroll
    for (int u = 0; u < 8; ++u) {
        float4 f = *reinterpret_cast<const float4*>(xr + 4 * t + 1024 * u);
        z[u] = {f.x, f.z};
    }
#pragma unroll
    for (int u = 8; u < 16; ++u) {
        float4 f = *reinterpret_cast<const float4*>(xr + (16380 - 4 * t - 1024 * u));
        z[u] = {-f.w, -f.y};
    }

    // ---- stage 1: radix-16, stride 256 ----
    dft16(z);
    twiddle16(z, (-2.0f * PI_F / 4096.0f) * (float)t);
#pragma unroll
    for (int s = 0; s < 16; ++s) stb(buf, t + (s << 8), z[s]);
    __syncthreads();

    // ---- stage 2: 16 sub-FFTs of length 256, stride 16 (in-place per thread) ----
    const int base2 = ((t >> 4) << 8) + (t & 15);
#pragma unroll
    for (int s = 0; s < 16; ++s) z[s] = ldb(buf, base2 + (s << 4));
    dft16(z);
    twiddle16(z, (-2.0f * PI_F / 256.0f) * (float)(t & 15));
#pragma unroll
    for (int s = 0; s < 16; ++s) stb(buf, base2 + (s << 4), z[s]);
    __syncthreads();

    // ---- stage 3: block b = nibswap(t), in-place RMW + write-back ----
    const int base3 = (((t & 15) << 4) | (t >> 4)) << 4;
#pragma unroll
    for (int w = 0; w < 8; ++w) {
        float4 v = *reinterpret_cast<const float4*>(&buf[SW(base3 + 2 * w)]);
        z[2 * w] = {v.x, v.y};
        z[2 * w + 1] = {v.z, v.w};
    }
    dft16(z);  // z[s] = Z[t + 256 s], kept in registers
#pragma unroll
    for (int w = 0; w < 8; ++w) {
        *reinterpret_cast<float4*>(&buf[SW(base3 + 2 * w)]) =
            make_float4(z[2 * w].x, z[2 * w].y, z[2 * w + 1].x, z[2 * w + 1].y);
    }
    __syncthreads();

    // ---- epilogue: partner read + real-FFT unpack + DST twiddle ----
    float s4, c4, s1, c1;
    __sincosf((PI_F / 4096.0f) * (float)t, &s4, &c4);
    __sincosf((PI_F / 16384.0f) * (float)t, &s1, &c1);
    const cpx w4 = {c4, -s4};  // e^{-i pi t/4096}
    const cpx w1 = {c1, s1};   // {cos, sin}(pi t/16384)

    // emit outputs for k = t + 256 s given Z1 = Z[k], Z2 = Z[4096-k]
    auto emit = [&](int s, cpx Z1, cpx Z2, bool writeLow) {
        const int k = t + (s << 8);
        cpx Ze = 0.5f * cpx{Z1.x + Z2.x, Z1.y - Z2.y};
        cpx Zo = 0.5f * cpx{Z1.y + Z2.y, Z2.x - Z1.x};
        cpx w4s = cmul(w4, cpx{C16[s], -S16[s]});
        cpx w1s = cmul(w1, cpx{C64[s], S64[s]});
        cpx V = Ze + cmul(w4s, Zo);
        yr[8191 - k] = fmaf(V.x, w1s.x, V.y * w1s.y);
        if (writeLow) yr[k - 1] = fmaf(V.x, w1s.y, -V.y * w1s.x);
    };

    if (t == 0) {
        // self-paired set: k = 256 s; partner slot (16-s)&15
#pragma unroll
        for (int s = 0; s < 16; ++s) emit(s, z[s], z[(16 - s) & 15], s > 0);
        yr[4095] = (z[0].x - z[0].y) * RT2O2;  // k = 4096 term
    } else {
        const int mu = 256 - t;
        const int pb = (((mu & 15) << 4) | (mu >> 4)) << 4;
        // partner unit j holds Z[mu + 256 j]; pairing j = 15 - s.
#pragma unroll
        for (int w = 0; w < 8; ++w) {
            float4 v = *reinterpret_cast<const float4*>(&buf[SW(pb + 2 * w)]);
            emit(15 - 2 * w, z[15 - 2 * w], cpx{v.x, v.y}, true);  // j = 2w
            emit(14 - 2 * w, z[14 - 2 * w], cpx{v.z, v.w}, true);  // j = 2w+1
        }
    }
}

extern "C" void kernel_launch(void* const* d_in, const int* in_sizes, int n_in,
                              void* d_out, int out_size, void* d_ws, size_t ws_size,
                              hipStream_t stream) {
    const float* x = (const float*)d_in[0];
    float* out = (float*)d_out;
    const int rows = in_sizes[0] / 8192;  // 4096
    dst_fft_kernel<<<rows / 2, THREADS, 0, stream>>>(x, out);
}

// Round 14
// 54.739 us; speedup vs baseline: 1.1521x; 1.1521x over previous
//
#include <hip/hip_runtime.h>

#define THREADS 256
#define PI_F 3.14159265358979323846f
#define RT2O2 0.70710678118654752440f

// Complex as native 2-float vector -> packed fp32 (v_pk_add/fma_f32).
typedef float cpx __attribute__((ext_vector_type(2)));

__device__ __forceinline__ cpx cmul(cpx a, cpx b) {
    cpx r = cpx{a.x, a.x} * b;
    return r + cpx{-a.y, a.y} * cpx{b.y, b.x};
}
__device__ __forceinline__ cpx mulni(cpx a) { return cpx{a.y, -a.x}; }   // * (-i)
__device__ __forceinline__ cpx mulpi(cpx a) { return cpx{-a.y, a.x}; }   // * (+i)

// XOR swizzle on cpx index (8B units): bits [3:1] ^= (bits[6:4]^bits[10:8]).
// Bit 0 untouched -> cpx-pair (float4) contiguity preserved.
__device__ __forceinline__ int SW(int i) { return i ^ ((((i >> 4) ^ (i >> 8)) & 7) << 1); }

__device__ __forceinline__ cpx ldb(const cpx* b, int i) { return b[SW(i)]; }
__device__ __forceinline__ void stb(cpx* b, int i, cpx v) { b[SW(i)] = v; }

// cos/sin(pi*s/16) and cos/sin(pi*s/64), s = 0..15 (compile-time folded).
constexpr float C16[16] = {
    1.f, 0.98078528040323044f, 0.92387953251128674f, 0.83146961230254524f,
    RT2O2, 0.55557023301960222f, 0.38268343236508978f, 0.19509032201612827f,
    0.f, -0.19509032201612827f, -0.38268343236508978f, -0.55557023301960222f,
    -RT2O2, -0.83146961230254524f, -0.92387953251128674f, -0.98078528040323044f};
constexpr float S16[16] = {
    0.f, 0.19509032201612827f, 0.38268343236508978f, 0.55557023301960222f,
    RT2O2, 0.83146961230254524f, 0.92387953251128674f, 0.98078528040323044f,
    1.f, 0.98078528040323044f, 0.92387953251128674f, 0.83146961230254524f,
    RT2O2, 0.55557023301960222f, 0.38268343236508978f, 0.19509032201612827f};
constexpr float C64[16] = {
    1.f, 0.99879545620517239f, 0.99518472667219693f, 0.98917650996478101f,
    0.98078528040323044f, 0.97003125319454397f, 0.95694033573220886f, 0.94154406518302081f,
    0.92387953251128674f, 0.90398929312344334f, 0.88192126434835503f, 0.85772861000027212f,
    0.83146961230254524f, 0.80320753148064494f, 0.77301045336273699f, 0.74095112535495911f};
constexpr float S64[16] = {
    0.f, 0.04906767432741801f, 0.09801714032956060f, 0.14673047445536175f,
    0.19509032201612827f, 0.24298017990326390f, 0.29028467725446233f, 0.33688985339222005f,
    0.38268343236508978f, 0.42755509343028208f, 0.47139673682599764f, 0.51410274419322166f,
    0.55557023301960222f, 0.59569930449243336f, 0.63439328416364549f, 0.67155895484701833f};

// In-place 16-point DFT, natural order in/out: z[s] = sum_n z[n] W16^{ns}
__device__ __forceinline__ void dft16(cpx* z) {
    cpx t[4][4];
#pragma unroll
    for (int n0 = 0; n0 < 4; ++n0) {
        cpx a = z[n0], b = z[4 + n0], c = z[8 + n0], d = z[12 + n0];
        cpx apc = a + c, amc = a - c, bpd = b + d, bmd = b - d;
        t[n0][0] = apc + bpd;
        t[n0][1] = amc + mulni(bmd);
        t[n0][2] = apc - bpd;
        t[n0][3] = amc + mulpi(bmd);
    }
    const cpx W1 = {0.92387953251128674f, -0.38268343236508978f};
    const cpx W2 = {RT2O2, -RT2O2};
    const cpx W3 = {0.38268343236508978f, -0.92387953251128674f};
    const cpx W6 = {-RT2O2, -RT2O2};
    const cpx W9 = {-0.92387953251128674f, 0.38268343236508978f};
    t[1][1] = cmul(t[1][1], W1); t[1][2] = cmul(t[1][2], W2); t[1][3] = cmul(t[1][3], W3);
    t[2][1] = cmul(t[2][1], W2); t[2][2] = mulni(t[2][2]);    t[2][3] = cmul(t[2][3], W6);
    t[3][1] = cmul(t[3][1], W3); t[3][2] = cmul(t[3][2], W6); t[3][3] = cmul(t[3][3], W9);
#pragma unroll
    for (int s0 = 0; s0 < 4; ++s0) {
        cpx a = t[0][s0], b = t[1][s0], c = t[2][s0], d = t[3][s0];
        cpx apc = a + c, amc = a - c, bpd = b + d, bmd = b - d;
        z[s0]      = apc + bpd;
        z[s0 + 4]  = amc + mulni(bmd);
        z[s0 + 8]  = apc - bpd;
        z[s0 + 12] = amc + mulpi(bmd);
    }
}

// z[s] *= w1^s, s=1..15; powers via squaring tree (dep depth ~4, not 15).
__device__ __forceinline__ void twiddle16(cpx* z, float theta) {
    float s_, c_;
    __sincosf(theta, &s_, &c_);
    cpx w1 = {c_, s_};
    cpx w2 = cmul(w1, w1), w3 = cmul(w1, w2), w4 = cmul(w2, w2);
    cpx w5 = cmul(w1, w4), w6 = cmul(w2, w4), w7 = cmul(w3, w4), w8 = cmul(w4, w4);
    cpx w9 = cmul(w1, w8), w10 = cmul(w2, w8), w11 = cmul(w3, w8), w12 = cmul(w4, w8);
    cpx w13 = cmul(w5, w8), w14 = cmul(w6, w8), w15 = cmul(w7, w8);
    z[1] = cmul(z[1], w1);   z[2] = cmul(z[2], w2);   z[3] = cmul(z[3], w3);
    z[4] = cmul(z[4], w4);   z[5] = cmul(z[5], w5);   z[6] = cmul(z[6], w6);
    z[7] = cmul(z[7], w7);   z[8] = cmul(z[8], w8);   z[9] = cmul(z[9], w9);
    z[10] = cmul(z[10], w10); z[11] = cmul(z[11], w11); z[12] = cmul(z[12], w12);
    z[13] = cmul(z[13], w13); z[14] = cmul(z[14], w14); z[15] = cmul(z[15], w15);
}

// One row per block (R10 structure). DST-II via N/2=4096 complex FFT
// (radices 16,16,16):
//   v = Makhoul(sign*x); z[m] = v[2m] + i*v[2m+1]; Z = FFT_4096(z)
//   V[k] = Ze[k] + e^{-i pi k/4096} Zo[k]; out[8191-k] = Re(V[k] e^{-i pi k/16384})
// Pair-folded epilogue: emit(k) and emit(4096-k) share (Z1,Z2):
//   Ze' = conj(Ze), Zo' = conj(Zo), w4s' = -conj(w4s)  =>  V' = conj(Ze - P),
//   P = w4s*Zo (already computed for V = Ze + P); phi' = pi/4 - phi =>
//   {c',s'} = {r(c+s), r(c-s)}, r = sqrt(2)/2.
// Each thread t handles s in [0,8) and emits 4 outputs per s. Only slots
// 8..15 of each stage-3 line are read by partner threads -> write back half.
// t=0: self-paired line (old full loop + Nyquist). t=128: pairs in own regs.
__global__ __launch_bounds__(THREADS) void dst_fft_kernel(const float* __restrict__ x,
                                                          float* __restrict__ out) {
    __shared__ __align__(16) cpx buf[4096];  // 32 KiB

    const int row = blockIdx.x;
    const float* __restrict__ xr = x + (size_t)row * 8192;
    float* __restrict__ yr = out + (size_t)row * 8192;
    const int t = threadIdx.x;

    cpx z[16];

    // ---- load in stage-1 butterfly order: m = t + 256u ----
#pragma unroll
    for (int u = 0; u < 8; ++u) {
        float4 f = *reinterpret_cast<const float4*>(xr + 4 * t + 1024 * u);
        z[u] = {f.x, f.z};
    }
#pragma unroll
    for (int u = 8; u < 16; ++u) {
        float4 f = *reinterpret_cast<const float4*>(xr + (16380 - 4 * t - 1024 * u));
        z[u] = {-f.w, -f.y};
    }

    // ---- stage 1: radix-16, stride 256 ----
    dft16(z);
    twiddle16(z, (-2.0f * PI_F / 4096.0f) * (float)t);
#pragma unroll
    for (int s = 0; s < 16; ++s) stb(buf, t + (s << 8), z[s]);
    __syncthreads();

    // ---- stage 2: 16 sub-FFTs of length 256, stride 16 (in-place per thread) ----
    const int base2 = ((t >> 4) << 8) + (t & 15);
#pragma unroll
    for (int s = 0; s < 16; ++s) z[s] = ldb(buf, base2 + (s << 4));
    dft16(z);
    twiddle16(z, (-2.0f * PI_F / 256.0f) * (float)(t & 15));
#pragma unroll
    for (int s = 0; s < 16; ++s) stb(buf, base2 + (s << 4), z[s]);
    __syncthreads();

    // ---- stage 3: block b = nibswap(t), in-place RMW; write back slots 8..15 ----
    const int base3 = (((t & 15) << 4) | (t >> 4)) << 4;
#pragma unroll
    for (int w = 0; w < 8; ++w) {
        float4 v = *reinterpret_cast<const float4*>(&buf[SW(base3 + 2 * w)]);
        z[2 * w] = {v.x, v.y};
        z[2 * w + 1] = {v.z, v.w};
    }
    dft16(z);  // z[s] = Z[t + 256 s], kept in registers
#pragma unroll
    for (int w = 4; w < 8; ++w) {  // only slots 8..15 are read by partners
        *reinterpret_cast<float4*>(&buf[SW(base3 + 2 * w)]) =
            make_float4(z[2 * w].x, z[2 * w].y, z[2 * w + 1].x, z[2 * w + 1].y);
    }
    __syncthreads();

    // ---- epilogue ----
    float s4, c4, s1, c1;
    __sincosf((PI_F / 4096.0f) * (float)t, &s4, &c4);
    __sincosf((PI_F / 16384.0f) * (float)t, &s1, &c1);
    const cpx w4 = {c4, -s4};  // e^{-i pi t/4096}
    const cpx w1 = {c1, s1};   // {cos, sin}(pi t/16384)

    // single-k emit (t=0 self-paired line only)
    auto emit = [&](int s, cpx Z1, cpx Z2, bool writeLow) {
        const int k = t + (s << 8);
        cpx Ze = 0.5f * cpx{Z1.x + Z2.x, Z1.y - Z2.y};
        cpx Zo = 0.5f * cpx{Z1.y + Z2.y, Z2.x - Z1.x};
        cpx w4s = cmul(w4, cpx{C16[s], -S16[s]});
        cpx w1s = cmul(w1, cpx{C64[s], S64[s]});
        cpx V = Ze + cmul(w4s, Zo);
        yr[8191 - k] = fmaf(V.x, w1s.x, V.y * w1s.y);
        if (writeLow) yr[k - 1] = fmaf(V.x, w1s.y, -V.y * w1s.x);
    };

    // pair emit: outputs for k = t+256s AND k' = 4096-k, s in [0,8)
    auto pair_emit = [&](int s, cpx Z1, cpx Z2) {
        const int k = t + (s << 8);
        cpx Ze = 0.5f * cpx{Z1.x + Z2.x, Z1.y - Z2.y};
        cpx Zo = 0.5f * cpx{Z1.y + Z2.y, Z2.x - Z1.x};
        cpx w4s = cmul(w4, cpx{C16[s], -S16[s]});
        cpx w1s = cmul(w1, cpx{C64[s], S64[s]});
        cpx P = cmul(w4s, Zo);
        cpx V = Ze + P;
        cpx Vp = {Ze.x - P.x, P.y - Ze.y};  // conj(Ze - P)
        yr[8191 - k] = fmaf(V.x, w1s.x, V.y * w1s.y);
        yr[k - 1]    = fmaf(V.x, w1s.y, -V.y * w1s.x);
        float cp_ = RT2O2 * (w1s.x + w1s.y);   // cos(pi/4 - phi)
        float sp_ = RT2O2 * (w1s.x - w1s.y);   // sin(pi/4 - phi)
        yr[4095 + k] = fmaf(Vp.x, cp_, Vp.y * sp_);
        yr[4095 - k] = fmaf(Vp.x, sp_, -Vp.y * cp_);
    };

    if (t == 0) {
        // self-paired set: k = 256 s; partner slot (16-s)&15
#pragma unroll
        for (int s = 0; s < 16; ++s) emit(s, z[s], z[(16 - s) & 15], s > 0);
        yr[4095] = (z[0].x - z[0].y) * RT2O2;  // k = 4096 term
    } else if (t == 128) {
        // line pairs with itself: Z[4096-k] = own slot 15-s
#pragma unroll
        for (int s = 0; s < 8; ++s) pair_emit(s, z[s], z[15 - s]);
    } else {
        const int mu = 256 - t;
        const int pb = (((mu & 15) << 4) | (mu >> 4)) << 4;
        // partner slots j = 15-s for s in [0,8) -> units w = 4..7
#pragma unroll
        for (int w = 4; w < 8; ++w) {
            float4 v = *reinterpret_cast<const float4*>(&buf[SW(pb + 2 * w)]);
            pair_emit(15 - 2 * w, z[15 - 2 * w], cpx{v.x, v.y});  // j = 2w
            pair_emit(14 - 2 * w, z[14 - 2 * w], cpx{v.z, v.w});  // j = 2w+1
        }
    }
}

extern "C" void kernel_launch(void* const* d_in, const int* in_sizes, int n_in,
                              void* d_out, int out_size, void* d_ws, size_t ws_size,
                              hipStream_t stream) {
    const float* x = (const float*)d_in[0];
    float* out = (float*)d_out;
    const int rows = in_sizes[0] / 8192;  // 4096
    dst_fft_kernel<<<rows, THREADS, 0, stream>>>(x, out);
}